// Round 1
// 155.841 us; speedup vs baseline: 1.0757x; 1.0757x over previous
//
#include <hip/hip_runtime.h>

#define BINS 10
#define TPB 256
#define MAX_BLOCKS 2048   // 8 blocks/CU * 256 CU -> full occupancy, grid-stride covers N

// Branchless register-resident histogram accumulate.
// All indexing of ssum/scnt is compile-time (fully unrolled) so the 20
// accumulators live in VGPRs, not scratch (rule: no runtime-indexed arrays).
__device__ __forceinline__ void ghmc_accum(float z, int t, float* ssum, float* scnt) {
    float tf = (float)t;
    float az = fabsf(z);
    float e  = __expf(-az);                  // exp(-|z|)
    float q  = 1.0f + e;
    float r  = __builtin_amdgcn_rcpf(q);     // ~1/(1+e)
    float s  = (z >= 0.0f) ? r : e * r;      // sigmoid(z)
    float g  = fabsf(s - tf);
    int bin  = (int)(g * 9.9999f);           // g>=0 so trunc == floor
    bin = bin < (BINS - 1) ? bin : (BINS - 1);
    // ce = logaddexp(0,z) - z*t = max(z,0) + log(1+exp(-|z|)) - z*t
    float ce = fmaxf(z, 0.0f) - z * tf + __logf(q);
    #pragma unroll
    for (int b = 0; b < BINS; ++b) {
        float mf = (bin == b) ? 1.0f : 0.0f;   // v_cmp + v_cndmask
        ssum[b] = fmaf(mf, ce, ssum[b]);       // v_fma
        scnt[b] += mf;                         // v_add
    }
}

__global__ __launch_bounds__(TPB) void ghmc_main(const float* __restrict__ x,
                                                 const int* __restrict__ tgt,
                                                 float* __restrict__ partial,  // [gridDim.x][2*BINS]
                                                 int nvec, int ntotal) {
    float ssum[BINS], scnt[BINS];
    #pragma unroll
    for (int b = 0; b < BINS; ++b) { ssum[b] = 0.0f; scnt[b] = 0.0f; }

    const float4* __restrict__ x4 = (const float4*)x;
    const int4*  __restrict__ t4 = (const int4*)tgt;
    const int tid = threadIdx.x;
    const int stride = gridDim.x * TPB;

    #pragma unroll 2
    for (int gi = blockIdx.x * TPB + tid; gi < nvec; gi += stride) {
        float4 xv = x4[gi];
        int4   tv = t4[gi];
        ghmc_accum(xv.x, tv.x, ssum, scnt);
        ghmc_accum(xv.y, tv.y, ssum, scnt);
        ghmc_accum(xv.z, tv.z, ssum, scnt);
        ghmc_accum(xv.w, tv.w, ssum, scnt);
    }
    // Scalar tail (N not a multiple of 4) — no-op for N = 2^24.
    if (blockIdx.x == 0) {
        for (int i = nvec * 4 + tid; i < ntotal; i += TPB)
            ghmc_accum(x[i], tgt[i], ssum, scnt);
    }

    // Wave-level shuffle reduce (64 lanes), then tiny LDS combine of the 4 waves.
    #pragma unroll
    for (int b = 0; b < BINS; ++b) {
        #pragma unroll
        for (int o = 32; o > 0; o >>= 1) {
            ssum[b] += __shfl_down(ssum[b], o);
            scnt[b] += __shfl_down(scnt[b], o);
        }
    }
    __shared__ float red[TPB / 64][2 * BINS];   // 320 B — no occupancy impact
    const int wid = tid >> 6, lane = tid & 63;
    if (lane == 0) {
        #pragma unroll
        for (int b = 0; b < BINS; ++b) {
            red[wid][b]        = ssum[b];
            red[wid][BINS + b] = scnt[b];
        }
    }
    __syncthreads();
    if (tid < 2 * BINS) {
        float v = 0.0f;
        #pragma unroll
        for (int w = 0; w < TPB / 64; ++w) v += red[w][tid];
        partial[blockIdx.x * (2 * BINS) + tid] = v;   // per-block partials: no atomics, no zero-kernel
    }
}

// result = sum_b sum_ce_b / max(cnt_b * nonempty, 1e-6)   (the N in beta cancels)
__global__ __launch_bounds__(TPB) void ghmc_final(const float* __restrict__ partial,
                                                  float* __restrict__ out, int nblocks) {
    float acc[2 * BINS];
    #pragma unroll
    for (int k = 0; k < 2 * BINS; ++k) acc[k] = 0.0f;
    for (int row = threadIdx.x; row < nblocks; row += TPB) {
        const float* p = partial + row * (2 * BINS);
        #pragma unroll
        for (int k = 0; k < 2 * BINS; ++k) acc[k] += p[k];
    }
    #pragma unroll
    for (int k = 0; k < 2 * BINS; ++k) {
        #pragma unroll
        for (int o = 32; o > 0; o >>= 1) acc[k] += __shfl_down(acc[k], o);
    }
    __shared__ float red[TPB / 64][2 * BINS];
    const int wid = threadIdx.x >> 6, lane = threadIdx.x & 63;
    if (lane == 0) {
        #pragma unroll
        for (int k = 0; k < 2 * BINS; ++k) red[wid][k] = acc[k];
    }
    __syncthreads();
    if (threadIdx.x == 0) {
        float ne = 0.0f;
        float sum[BINS], cnt[BINS];
        #pragma unroll
        for (int b = 0; b < BINS; ++b) {
            float s = 0.0f, c = 0.0f;
            #pragma unroll
            for (int w = 0; w < TPB / 64; ++w) { s += red[w][b]; c += red[w][BINS + b]; }
            sum[b] = s; cnt[b] = c;
            ne += (c > 0.0f) ? 1.0f : 0.0f;
        }
        float res = 0.0f;
        #pragma unroll
        for (int b = 0; b < BINS; ++b)
            res += sum[b] / fmaxf(cnt[b] * ne, 1e-6f);
        out[0] = res;
    }
}

extern "C" void kernel_launch(void* const* d_in, const int* in_sizes, int n_in,
                              void* d_out, int out_size, void* d_ws, size_t ws_size,
                              hipStream_t stream) {
    const float* x   = (const float*)d_in[0];
    const int*   tgt = (const int*)d_in[1];
    float* out     = (float*)d_out;
    float* partial = (float*)d_ws;

    int N    = in_sizes[0];
    int nvec = N / 4;

    int blocks = MAX_BLOCKS;
    int maxrows = (int)(ws_size / (2 * BINS * sizeof(float)));   // stay inside workspace
    if (blocks > maxrows) blocks = maxrows;
    int need = (nvec + TPB - 1) / TPB;
    if (blocks > need) blocks = need;
    if (blocks < 1) blocks = 1;

    ghmc_main<<<blocks, TPB, 0, stream>>>(x, tgt, partial, nvec, N);
    ghmc_final<<<1, TPB, 0, stream>>>(partial, out, blocks);
}

// Round 3
// 152.547 us; speedup vs baseline: 1.0990x; 1.0216x over previous
//
#include <hip/hip_runtime.h>

#define BINS 10
#define TPB 256
#define MAX_BLOCKS 2048   // 8 blocks/CU * 256 CU -> full occupancy, grid-stride covers N
#define NTHR 9            // bin thresholds k=1..9 in u-space

// u-space bin boundaries: c_k = ln(k / (9.9999 - k))  (logit of k/9.9999).
// bin(sigmoid(u)) >= k  <=>  u >= c_k   (sigmoid monotone).
__device__ __constant__ const float c_thr[NTHR] = {
    -2.1972135f, -1.3862819f, -0.8472836f, -0.4054484f, 2.00002e-5f,
     0.4054901f,  0.8473312f,  1.3863444f,  2.1973246f
};

// Register-resident suffix-histogram accumulate.
// A[0]  += ce (total);  A[k] += ce*(u>=c_k);  C[k-1] += (u>=c_k), k=1..9.
// All indexing compile-time (fully unrolled) -> accumulators stay in VGPRs.
__device__ __forceinline__ void ghmc_accum(float z, int t, float* A, float* C) {
    // t in {0,1}:  g = |sigmoid(z)-t| = sigmoid(u),  ce = softplus(u),
    // with u = (t ? -z : z) = z with sign bit xor'd by t.
    unsigned ub = __float_as_uint(z) ^ ((unsigned)t << 31);
    float u  = __uint_as_float(ub);
    // softplus(u) = max(u,0) + log(1 + exp(-|u|)); bit-identical to the
    // round-1 kernel's max(z,0) - z*t + log(1+exp(-|z|)) since |u|=|z|.
    float e  = __expf(-fabsf(u));                  // v_mul + v_exp
    float q  = 1.0f + e;
    float ce = fmaxf(u, 0.0f) + __logf(q);         // v_max + v_log(+mul) + v_add
    A[0] += ce;
    #pragma unroll
    for (int k = 1; k <= NTHR; ++k) {
        float m = (u >= c_thr[k - 1]) ? 1.0f : 0.0f;  // v_cmp + v_cndmask
        A[k]    = fmaf(m, ce, A[k]);                  // v_fma
        C[k - 1] += m;                                // v_add
    }
}

__global__ __launch_bounds__(TPB) void ghmc_main(const float* __restrict__ x,
                                                 const int* __restrict__ tgt,
                                                 float* __restrict__ partial,  // [gridDim.x][2*BINS]
                                                 int nvec, int ntotal) {
    float A[BINS];   // A[0]=total ce, A[k]=suffix ce-sum for threshold k
    float C[NTHR];   // suffix counts for thresholds 1..9
    #pragma unroll
    for (int b = 0; b < BINS; ++b) A[b] = 0.0f;
    #pragma unroll
    for (int k = 0; k < NTHR; ++k) C[k] = 0.0f;

    const float4* __restrict__ x4 = (const float4*)x;
    const int4*  __restrict__ t4 = (const int4*)tgt;
    const int tid = threadIdx.x;
    const int stride = gridDim.x * TPB;

    #pragma unroll 2
    for (int gi = blockIdx.x * TPB + tid; gi < nvec; gi += stride) {
        float4 xv = x4[gi];
        int4   tv = t4[gi];
        ghmc_accum(xv.x, tv.x, A, C);
        ghmc_accum(xv.y, tv.y, A, C);
        ghmc_accum(xv.z, tv.z, A, C);
        ghmc_accum(xv.w, tv.w, A, C);
    }
    // Scalar tail (N not a multiple of 4) — no-op for N = 2^24.
    if (blockIdx.x == 0) {
        for (int i = nvec * 4 + tid; i < ntotal; i += TPB)
            ghmc_accum(x[i], tgt[i], A, C);
    }

    // Wave-level shuffle reduce (64 lanes), then tiny LDS combine of the 4 waves.
    #pragma unroll
    for (int b = 0; b < BINS; ++b) {
        #pragma unroll
        for (int o = 32; o > 0; o >>= 1) A[b] += __shfl_down(A[b], o);
    }
    #pragma unroll
    for (int k = 0; k < NTHR; ++k) {
        #pragma unroll
        for (int o = 32; o > 0; o >>= 1) C[k] += __shfl_down(C[k], o);
    }
    __shared__ float red[TPB / 64][2 * BINS];   // 320 B — no occupancy impact
    const int wid = tid >> 6, lane = tid & 63;
    if (lane == 0) {
        #pragma unroll
        for (int b = 0; b < BINS; ++b) red[wid][b] = A[b];
        #pragma unroll
        for (int k = 0; k < NTHR; ++k) red[wid][BINS + k] = C[k];
    }
    __syncthreads();
    if (tid < BINS + NTHR) {
        float v = 0.0f;
        #pragma unroll
        for (int w = 0; w < TPB / 64; ++w) v += red[w][tid];
        partial[blockIdx.x * (2 * BINS) + tid] = v;   // per-block partials: no atomics
    }
}

// Recover per-bin sums/counts from suffix accumulators, then
// result = sum_b sum_ce_b / max(cnt_b * nonempty, 1e-6)   (the N in beta cancels)
__global__ __launch_bounds__(TPB) void ghmc_final(const float* __restrict__ partial,
                                                  float* __restrict__ out,
                                                  int nblocks, int ntotal) {
    float acc[2 * BINS];
    #pragma unroll
    for (int k = 0; k < 2 * BINS; ++k) acc[k] = 0.0f;
    for (int row = threadIdx.x; row < nblocks; row += TPB) {
        const float* p = partial + row * (2 * BINS);
        #pragma unroll
        for (int k = 0; k < 2 * BINS; ++k) acc[k] += p[k];
    }
    #pragma unroll
    for (int k = 0; k < 2 * BINS; ++k) {
        #pragma unroll
        for (int o = 32; o > 0; o >>= 1) acc[k] += __shfl_down(acc[k], o);
    }
    __shared__ float red[TPB / 64][2 * BINS];
    const int wid = threadIdx.x >> 6, lane = threadIdx.x & 63;
    if (lane == 0) {
        #pragma unroll
        for (int k = 0; k < 2 * BINS; ++k) red[wid][k] = acc[k];
    }
    __syncthreads();
    if (threadIdx.x == 0) {
        float A[BINS + 1], C[BINS + 1];
        #pragma unroll
        for (int b = 0; b < BINS; ++b) {
            float v = 0.0f;
            #pragma unroll
            for (int w = 0; w < TPB / 64; ++w) v += red[w][b];
            A[b] = v;
        }
        A[BINS] = 0.0f;
        C[0] = (float)ntotal;          // exact: ntotal <= 2^24
        #pragma unroll
        for (int k = 1; k <= NTHR; ++k) {
            float v = 0.0f;
            #pragma unroll
            for (int w = 0; w < TPB / 64; ++w) v += red[w][BINS + k - 1];
            C[k] = v;
        }
        C[BINS] = 0.0f;
        float ne = 0.0f;
        #pragma unroll
        for (int b = 0; b < BINS; ++b) {
            float c = C[b] - C[b + 1];
            ne += (c > 0.0f) ? 1.0f : 0.0f;
        }
        float res = 0.0f;
        #pragma unroll
        for (int b = 0; b < BINS; ++b) {
            float s = A[b] - A[b + 1];
            float c = C[b] - C[b + 1];
            res += s / fmaxf(c * ne, 1e-6f);
        }
        out[0] = res;
    }
}

extern "C" void kernel_launch(void* const* d_in, const int* in_sizes, int n_in,
                              void* d_out, int out_size, void* d_ws, size_t ws_size,
                              hipStream_t stream) {
    const float* x   = (const float*)d_in[0];
    const int*   tgt = (const int*)d_in[1];
    float* out     = (float*)d_out;
    float* partial = (float*)d_ws;

    int N    = in_sizes[0];
    int nvec = N / 4;

    int blocks = MAX_BLOCKS;
    int maxrows = (int)(ws_size / (2 * BINS * sizeof(float)));   // stay inside workspace
    if (blocks > maxrows) blocks = maxrows;
    int need = (nvec + TPB - 1) / TPB;
    if (blocks > need) blocks = need;
    if (blocks < 1) blocks = 1;

    ghmc_main<<<blocks, TPB, 0, stream>>>(x, tgt, partial, nvec, N);
    ghmc_final<<<1, TPB, 0, stream>>>(partial, out, blocks, N);
}